// Round 15
// baseline (38.627 us; speedup 1.0000x reference)
//
#include <hip/hip_runtime.h>
#include <math.h>

// Sizes fixed by the reference.
#define BSZ  16
#define DIM  1024
#define DPB  16        // d-channels per tile
#define THREADS 1024   // waves 0-7 compute, waves 8-15 memory
#define TPB  4         // tiles per block (b = 4*bq + k), grid = 256 = 1 block/CU
#define SSTRIDE 17     // LDS float-stride per s-cell: 17*31=527==15 (mod 32)
#define BUFF 17472     // floats per buffer (covers prefetch overrun)
#define LDSB (2 * BUFF * 4)   // 139776 B -> 1 block/CU

__device__ __forceinline__ float sigmoidf_(float v) {
    return __builtin_amdgcn_rcpf(1.0f + __expf(-v));
}

// Barrier without __syncthreads()'s implicit vmcnt(0) drain.
__device__ __forceinline__ void soft_barrier() {
    asm volatile("s_waitcnt lgkmcnt(0)" ::: "memory");
    __builtin_amdgcn_s_barrier();
    asm volatile("" ::: "memory");
}

extern __shared__ float xs[];

// 2D SSM run as the recurrence directly on x (== causal conv with the impulse
// response == reference FFT path, by linearity/shift-invariance/causality).
//
// R15 = R14 + per-block s-phase XOR (channel decorrelation).
// R14 analysis: effective BW pinned at ~3.4 TB/s while the harness's fill
// kernel hits 6.7. Our addresses are base + s*64KB; with ~4KB channel
// interleave over ~128 channels, 16s mod 128 gives each block only 8-16
// distinct channel positions, and all blocks sweep s in the same
// barrier-synced order -> machine-wide concentration on ~10% of channels.
// Fix: each block visits s in the order s ^ ph (ph = blockid*73 & 127) in
// ALL global mappings; the LDS slot follows the permuted s, so the compute
// loop is untouched. XOR preserves 64B d-group contiguity and LDS bank
// structure (constant XOR permutes s within [0,128) and residues mod 32).
__global__ __launch_bounds__(THREADS, 1) void ssm2d_kernel(
    const float* __restrict__ x,
    const float* __restrict__ A1, const float* __restrict__ A2,
    const float* __restrict__ B1, const float* __restrict__ B2,
    const float* __restrict__ C1, const float* __restrict__ C2,
    const float* __restrict__ omega,
    float* __restrict__ out)
{
    // ---- XCD-contiguity swizzle (R14) ----
    const int lx   = blockIdx.x;           // 0..255
    const int xcd  = lx & 7;
    const int hi   = (lx >> 3) & 7;
    const int bq   = lx >> 6;              // 0..3 -> tiles b = 4*bq + k
    const int dgrp = 8 * xcd + hi;         // 0..63
    const int d0   = dgrp * DPB;
    const int ph   = (lx * 73) & 127;      // channel-decorrelation phase
    const int t    = threadIdx.x;

    const int lane = t & 63;
    const int wv   = t >> 6;               // wave 0..15
    const int i    = lane & 31;            // compute: row owned by this lane

    // ---- compute-wave coefficients (waves 0-7 only) ----
    float a1c0, a1c1, a2c0, a2c1, b1c0, b1c1, b2c0, b2c1;
    float c1s0, c1s1, c2s0, c2s1, om;
    float a1z0, a1z1, a2z0, a2z1;
    int dd = 0;
    if (t < 512) {
        dd = 2 * wv + (lane >> 5);         // image (d-index) 0..15
        const int d = d0 + dd;
        const float2 fA1 = *reinterpret_cast<const float2*>(A1 + 2 * d);
        const float2 fA2 = *reinterpret_cast<const float2*>(A2 + 2 * d);
        const float2 fB1 = *reinterpret_cast<const float2*>(B1 + 2 * d);
        const float2 fB2 = *reinterpret_cast<const float2*>(B2 + 2 * d);
        const float2 fC1 = *reinterpret_cast<const float2*>(C1 + 2 * d);
        const float2 fC2 = *reinterpret_cast<const float2*>(C2 + 2 * d);
        om   = omega[d];
        a1c0 = sigmoidf_(fA1.x) * 0.5f;  a1c1 = sigmoidf_(fA1.y) * 0.5f;
        a2c0 = sigmoidf_(fA2.x) * 0.5f;  a2c1 = sigmoidf_(fA2.y) * 0.5f;
        b1c0 = sigmoidf_(fB1.x) * 0.5f;  b1c1 = sigmoidf_(fB1.y) * 0.5f;
        b2c0 = sigmoidf_(fB2.x) * 0.5f;  b2c1 = sigmoidf_(fB2.y) * 0.5f;
        const float sc = 0.70710678118654752f;
        c1s0 = fC1.x * sc;  c1s1 = fC1.y * sc;
        c2s0 = fC2.x * sc;  c2s1 = fC2.y * sc;
        a1z0 = (i == 0) ? 0.f : a1c0;  a1z1 = (i == 0) ? 0.f : a1c1;
        a2z0 = (i == 0) ? 0.f : a2c0;  a2z1 = (i == 0) ? 0.f : a2c1;
    }

    // ---- memory-wave mappings (s-rows visited in XOR-permuted order) ----
    const int m     = t & 511;
    const int srowX = ((m >> 2) ^ ph) & 127;   // permuted s-row 0..127
    const int qq    = (m & 3) * 4;
    const size_t gb = (size_t)srowX * (BSZ * DIM) + d0 + qq;
    float4 L[8];

#define ISSUE(TILE) do {                                                     \
        const float* gp = x + gb + (size_t)(TILE) * DIM;                     \
        _Pragma("unroll") for (int k2 = 0; k2 < 8; ++k2)                     \
            L[k2] = *reinterpret_cast<const float4*>(                        \
                gp + (size_t)k2 * (128 * BSZ * DIM));                        \
    } while (0)

#define STAGEFROM(BUFO) do {                                                 \
        _Pragma("unroll") for (int k2 = 0; k2 < 8; ++k2) {                   \
            float* p = (BUFO) + SSTRIDE * (srowX + 128 * k2) + qq;           \
            p[0] = L[k2].x; p[1] = L[k2].y;                                  \
            p[2] = L[k2].z; p[3] = L[k2].w; }                                \
    } while (0)

#define DRAINTO(TILE, BUFO) do {                                             \
        float* op = out + gb + (size_t)(TILE) * DIM;                         \
        _Pragma("unroll") for (int k2 = 0; k2 < 8; ++k2) {                   \
            const float* p = (BUFO) + SSTRIDE * (srowX + 128 * k2) + qq;     \
            float4 v; v.x = p[0]; v.y = p[1]; v.z = p[2]; v.w = p[3];        \
            *reinterpret_cast<float4*>(                                      \
                op + (size_t)k2 * (128 * BSZ * DIM)) = v; }                  \
    } while (0)

    // ---- prologue: all 1024 threads stage tile 0 (permuted s order) ----
    {
        const int srow4X = ((t >> 2) ^ ph) & 255;  // ph<128 keeps range
        const int qq4    = (t & 3) * 4;
        const float* gp0 = x + (size_t)srow4X * (BSZ * DIM)
                             + (size_t)(4 * bq) * DIM + d0 + qq4;
        float4 P[4];
        #pragma unroll
        for (int k2 = 0; k2 < 4; ++k2)
            P[k2] = *reinterpret_cast<const float4*>(
                gp0 + (size_t)k2 * (256 * BSZ * DIM));
        #pragma unroll
        for (int k2 = 0; k2 < 4; ++k2) {
            float* p = xs + SSTRIDE * (srow4X + 256 * k2) + qq4;
            p[0] = P[k2].x; p[1] = P[k2].y; p[2] = P[k2].z; p[3] = P[k2].w;
        }
    }
    soft_barrier();

    // ---- compute step macros ----
#define SBODY(XV_EXPR)                                                       \
        const float xv = (XV_EXPR);                                          \
        const float t10 = b1c0 * xv, t11 = b1c1 * xv;                        \
        const float hn0 = fmaf(a1c0, h0, fmaf(a2c0, v0, t10));               \
        const float hn1 = fmaf(a1c1, h1, fmaf(a2c1, v1, t11));               \
        float vn0 = b2c0 * xv, vn1 = b2c1 * xv;                              \
        asm("s_nop 1\n\t"                                                    \
            "v_fmac_f32_dpp %0, %2, %6 wave_shr:1 row_mask:0xf bank_mask:0xf bound_ctrl:0\n\t" \
            "v_fmac_f32_dpp %1, %3, %7 wave_shr:1 row_mask:0xf bank_mask:0xf bound_ctrl:0\n\t" \
            "v_fmac_f32_dpp %0, %4, %8 wave_shr:1 row_mask:0xf bank_mask:0xf bound_ctrl:0\n\t" \
            "v_fmac_f32_dpp %1, %5, %9 wave_shr:1 row_mask:0xf bank_mask:0xf bound_ctrl:0"     \
            : "+v"(vn0), "+v"(vn1)                                           \
            : "v"(h0), "v"(h1), "v"(v0), "v"(v1),                            \
              "v"(a2z0), "v"(a2z1), "v"(a1z0), "v"(a1z1));                   \
        float y = hn0 * c1s0;                                                \
        y = fmaf(hn1, c1s1, y);                                              \
        y = fmaf(vn0, c2s0, y);                                              \
        y = fmaf(vn1, c2s1, y);                                              \
        const float z = fmaf(xv, om, y);                                     \
        const float o = z * sigmoidf_(z);

#define SSTEP_PRE(TS, XQ) do {                                               \
        const bool val = (i <= (TS));                                        \
        SBODY(val ? (XQ) : 0.f)                                              \
        if (val) rp[SSTRIDE * (TS)] = o;                                     \
        h0 = hn0; h1 = hn1; v0 = vn0; v1 = vn1; } while (0)

#define SSTEP_POST(TS, XQ) do { SBODY(XQ)                                    \
        if (i >= (TS) - 31) rp[SSTRIDE * (TS)] = o;                          \
        h0 = hn0; h1 = hn1; v0 = vn0; v1 = vn1; } while (0)

    // ---- main loop: one soft barrier per tile ----
    #pragma unroll 1
    for (int k = 0; k < TPB; ++k) {
        if (t < 512) {
            // -------- compute waves --------
            float* rp = xs + (k & 1) * BUFF + 527 * i + dd;
            float h0 = 0.f, h1 = 0.f, v0 = 0.f, v1 = 0.f;
            float xq0 = rp[0 * SSTRIDE];
            float xq1 = rp[1 * SSTRIDE];
            float xq2 = rp[2 * SSTRIDE];
            #pragma unroll
            for (int ts = 0; ts < 30; ts += 3) {
                SSTEP_PRE(ts + 0, xq0); xq0 = rp[SSTRIDE * (ts + 3)];
                SSTEP_PRE(ts + 1, xq1); xq1 = rp[SSTRIDE * (ts + 4)];
                SSTEP_PRE(ts + 2, xq2); xq2 = rp[SSTRIDE * (ts + 5)];
            }
            SSTEP_PRE(30, xq0); xq0 = rp[SSTRIDE * 33];
            #pragma unroll
            for (int ts = 31; ts < 61; ts += 3) {
                SSTEP_POST(ts + 0, xq1); xq1 = rp[SSTRIDE * (ts + 3)];
                SSTEP_POST(ts + 1, xq2); xq2 = rp[SSTRIDE * (ts + 4)];
                SSTEP_POST(ts + 2, xq0); xq0 = rp[SSTRIDE * (ts + 5)];
            }
            SSTEP_POST(61, xq1);
            SSTEP_POST(62, xq2);
        } else {
            // -------- memory waves (R7 order: issue, drain, stage) --------
            float* bufO = xs + ((k + 1) & 1) * BUFF;
            if (k < TPB - 1) ISSUE(4 * bq + k + 1);      // head start
            if (k >= 1) DRAINTO(4 * bq + k - 1, bufO);   // read bufO first
            if (k < TPB - 1) STAGEFROM(bufO);            // consume same-phase L
        }
        soft_barrier();
    }

    // ---- epilogue: all 1024 threads drain tile 3 (permuted s order) ----
    {
        const int srow4X = ((t >> 2) ^ ph) & 255;
        const int qq4    = (t & 3) * 4;
        const float* bufE = xs + ((TPB - 1) & 1) * BUFF;
        float* op = out + (size_t)srow4X * (BSZ * DIM)
                        + (size_t)(4 * bq + TPB - 1) * DIM + d0 + qq4;
        #pragma unroll
        for (int k2 = 0; k2 < 4; ++k2) {
            const float* p = bufE + SSTRIDE * (srow4X + 256 * k2) + qq4;
            float4 v; v.x = p[0]; v.y = p[1]; v.z = p[2]; v.w = p[3];
            *reinterpret_cast<float4*>(op + (size_t)k2 * (256 * BSZ * DIM)) = v;
        }
    }
}

extern "C" void kernel_launch(void* const* d_in, const int* in_sizes, int n_in,
                              void* d_out, int out_size, void* d_ws, size_t ws_size,
                              hipStream_t stream) {
    const float* x     = (const float*)d_in[0];
    const float* A1    = (const float*)d_in[1];
    const float* A2    = (const float*)d_in[2];
    const float* B1    = (const float*)d_in[3];
    const float* B2    = (const float*)d_in[4];
    const float* C1    = (const float*)d_in[5];
    const float* C2    = (const float*)d_in[6];
    const float* omega = (const float*)d_in[7];
    float* out = (float*)d_out;

    (void)hipFuncSetAttribute(reinterpret_cast<const void*>(ssm2d_kernel),
                              hipFuncAttributeMaxDynamicSharedMemorySize, LDSB);

    dim3 grid(256);                 // 64 d-groups x 4 b-quads; 4 tiles/block
    dim3 block(THREADS);
    hipLaunchKernelGGL(ssm2d_kernel, grid, block, LDSB, stream,
                       x, A1, A2, B1, B2, C1, C2, omega, out);
}

// Round 17
// 38.400 us; speedup vs baseline: 1.0059x; 1.0059x over previous
//
#include <hip/hip_runtime.h>
#include <math.h>

// Sizes fixed by the reference.
#define BSZ  16
#define DIM  1024
#define DPB  16        // d-channels per tile
#define THREADS 1024   // waves 0-7 compute, waves 8-15 memory
#define TPB  4         // tiles per block (b = 4*bq + k), grid = 256 = 1 block/CU
#define SSTRIDE 17     // LDS float-stride per s-cell: 17*31=527==15 (mod 32)
#define BUFF 17472     // floats per buffer (covers prefetch overrun)
#define LDSB (2 * BUFF * 4)   // 139776 B -> 1 block/CU

typedef float vfloat4 __attribute__((ext_vector_type(4)));  // native vec for NT store

__device__ __forceinline__ float sigmoidf_(float v) {
    return __builtin_amdgcn_rcpf(1.0f + __expf(-v));
}

// Barrier without __syncthreads()'s implicit vmcnt(0) drain.
__device__ __forceinline__ void soft_barrier() {
    asm volatile("s_waitcnt lgkmcnt(0)" ::: "memory");
    __builtin_amdgcn_s_barrier();
    asm volatile("" ::: "memory");
}

extern __shared__ float xs[];

// 2D SSM run as the recurrence directly on x (== causal conv with the impulse
// response == reference FFT path, by linearity/shift-invariance/causality).
//
// R17 = R16 with the NT-store type fixed (ext_vector_type(4) float — clang's
// builtin rejects HIP_vector_type). Structure: R14 exactly (best 38.49us:
// XCD-contiguity swizzle, R7 memory order, soft barriers, PRE/POST masks)
// + NONTEMPORAL drain stores: out is never re-read, so drains stream
// through L2 without write-allocating -> L2 capacity stays with the x read
// stream, no RMW merges on 64B half-lines.
__global__ __launch_bounds__(THREADS, 1) void ssm2d_kernel(
    const float* __restrict__ x,
    const float* __restrict__ A1, const float* __restrict__ A2,
    const float* __restrict__ B1, const float* __restrict__ B2,
    const float* __restrict__ C1, const float* __restrict__ C2,
    const float* __restrict__ omega,
    float* __restrict__ out)
{
    // ---- XCD-contiguity swizzle: XCD = lx&7 hosts dgrps 8*(lx&7)+hi ----
    const int lx   = blockIdx.x;           // 0..255
    const int xcd  = lx & 7;
    const int hi   = (lx >> 3) & 7;
    const int bq   = lx >> 6;              // 0..3 -> tiles b = 4*bq + k
    const int dgrp = 8 * xcd + hi;         // 0..63
    const int d0   = dgrp * DPB;
    const int t    = threadIdx.x;

    const int lane = t & 63;
    const int wv   = t >> 6;               // wave 0..15
    const int i    = lane & 31;            // compute: row owned by this lane

    // ---- compute-wave coefficients (waves 0-7 only) ----
    float a1c0, a1c1, a2c0, a2c1, b1c0, b1c1, b2c0, b2c1;
    float c1s0, c1s1, c2s0, c2s1, om;
    float a1z0, a1z1, a2z0, a2z1;
    int dd = 0;
    if (t < 512) {
        dd = 2 * wv + (lane >> 5);         // image (d-index) 0..15
        const int d = d0 + dd;
        const float2 fA1 = *reinterpret_cast<const float2*>(A1 + 2 * d);
        const float2 fA2 = *reinterpret_cast<const float2*>(A2 + 2 * d);
        const float2 fB1 = *reinterpret_cast<const float2*>(B1 + 2 * d);
        const float2 fB2 = *reinterpret_cast<const float2*>(B2 + 2 * d);
        const float2 fC1 = *reinterpret_cast<const float2*>(C1 + 2 * d);
        const float2 fC2 = *reinterpret_cast<const float2*>(C2 + 2 * d);
        om   = omega[d];
        a1c0 = sigmoidf_(fA1.x) * 0.5f;  a1c1 = sigmoidf_(fA1.y) * 0.5f;
        a2c0 = sigmoidf_(fA2.x) * 0.5f;  a2c1 = sigmoidf_(fA2.y) * 0.5f;
        b1c0 = sigmoidf_(fB1.x) * 0.5f;  b1c1 = sigmoidf_(fB1.y) * 0.5f;
        b2c0 = sigmoidf_(fB2.x) * 0.5f;  b2c1 = sigmoidf_(fB2.y) * 0.5f;
        const float sc = 0.70710678118654752f;
        c1s0 = fC1.x * sc;  c1s1 = fC1.y * sc;
        c2s0 = fC2.x * sc;  c2s1 = fC2.y * sc;
        a1z0 = (i == 0) ? 0.f : a1c0;  a1z1 = (i == 0) ? 0.f : a1c1;
        a2z0 = (i == 0) ? 0.f : a2c0;  a2z1 = (i == 0) ? 0.f : a2c1;
    }

    // ---- memory-wave mappings & load set ----
    const int m    = t & 511;
    const int srow = m >> 2;               // 0..127
    const int qq   = (m & 3) * 4;
    const size_t gb = (size_t)srow * (BSZ * DIM) + d0 + qq;
    float4 L[8];

#define ISSUE(TILE) do {                                                     \
        const float* gp = x + gb + (size_t)(TILE) * DIM;                     \
        _Pragma("unroll") for (int k2 = 0; k2 < 8; ++k2)                     \
            L[k2] = *reinterpret_cast<const float4*>(                        \
                gp + (size_t)k2 * (128 * BSZ * DIM));                        \
    } while (0)

#define STAGEFROM(BUFO) do {                                                 \
        _Pragma("unroll") for (int k2 = 0; k2 < 8; ++k2) {                   \
            float* p = (BUFO) + SSTRIDE * (srow + 128 * k2) + qq;            \
            p[0] = L[k2].x; p[1] = L[k2].y;                                  \
            p[2] = L[k2].z; p[3] = L[k2].w; }                                \
    } while (0)

#define DRAINTO(TILE, BUFO) do {                                             \
        float* op = out + gb + (size_t)(TILE) * DIM;                         \
        _Pragma("unroll") for (int k2 = 0; k2 < 8; ++k2) {                   \
            const float* p = (BUFO) + SSTRIDE * (srow + 128 * k2) + qq;      \
            vfloat4 v; v.x = p[0]; v.y = p[1]; v.z = p[2]; v.w = p[3];       \
            __builtin_nontemporal_store(v, reinterpret_cast<vfloat4*>(       \
                op + (size_t)k2 * (128 * BSZ * DIM))); }                     \
    } while (0)

    // ---- prologue: all 1024 threads stage tile 0 into buf0 ----
    {
        const int srow4 = t >> 2;          // 0..255
        const int qq4   = (t & 3) * 4;
        const float* gp0 = x + (size_t)srow4 * (BSZ * DIM)
                             + (size_t)(4 * bq) * DIM + d0 + qq4;
        float4 P[4];
        #pragma unroll
        for (int k2 = 0; k2 < 4; ++k2)
            P[k2] = *reinterpret_cast<const float4*>(
                gp0 + (size_t)k2 * (256 * BSZ * DIM));
        #pragma unroll
        for (int k2 = 0; k2 < 4; ++k2) {
            float* p = xs + SSTRIDE * (srow4 + 256 * k2) + qq4;
            p[0] = P[k2].x; p[1] = P[k2].y; p[2] = P[k2].z; p[3] = P[k2].w;
        }
    }
    soft_barrier();

    // ---- compute step macros ----
#define SBODY(XV_EXPR)                                                       \
        const float xv = (XV_EXPR);                                          \
        const float t10 = b1c0 * xv, t11 = b1c1 * xv;                        \
        const float hn0 = fmaf(a1c0, h0, fmaf(a2c0, v0, t10));               \
        const float hn1 = fmaf(a1c1, h1, fmaf(a2c1, v1, t11));               \
        float vn0 = b2c0 * xv, vn1 = b2c1 * xv;                              \
        asm("s_nop 1\n\t"                                                    \
            "v_fmac_f32_dpp %0, %2, %6 wave_shr:1 row_mask:0xf bank_mask:0xf bound_ctrl:0\n\t" \
            "v_fmac_f32_dpp %1, %3, %7 wave_shr:1 row_mask:0xf bank_mask:0xf bound_ctrl:0\n\t" \
            "v_fmac_f32_dpp %0, %4, %8 wave_shr:1 row_mask:0xf bank_mask:0xf bound_ctrl:0\n\t" \
            "v_fmac_f32_dpp %1, %5, %9 wave_shr:1 row_mask:0xf bank_mask:0xf bound_ctrl:0"     \
            : "+v"(vn0), "+v"(vn1)                                           \
            : "v"(h0), "v"(h1), "v"(v0), "v"(v1),                            \
              "v"(a2z0), "v"(a2z1), "v"(a1z0), "v"(a1z1));                   \
        float y = hn0 * c1s0;                                                \
        y = fmaf(hn1, c1s1, y);                                              \
        y = fmaf(vn0, c2s0, y);                                              \
        y = fmaf(vn1, c2s1, y);                                              \
        const float z = fmaf(xv, om, y);                                     \
        const float o = z * sigmoidf_(z);

#define SSTEP_PRE(TS, XQ) do {                                               \
        const bool val = (i <= (TS));                                        \
        SBODY(val ? (XQ) : 0.f)                                              \
        if (val) rp[SSTRIDE * (TS)] = o;                                     \
        h0 = hn0; h1 = hn1; v0 = vn0; v1 = vn1; } while (0)

#define SSTEP_POST(TS, XQ) do { SBODY(XQ)                                    \
        if (i >= (TS) - 31) rp[SSTRIDE * (TS)] = o;                          \
        h0 = hn0; h1 = hn1; v0 = vn0; v1 = vn1; } while (0)

    // ---- main loop: one soft barrier per tile ----
    #pragma unroll 1
    for (int k = 0; k < TPB; ++k) {
        if (t < 512) {
            // -------- compute waves --------
            float* rp = xs + (k & 1) * BUFF + 527 * i + dd;
            float h0 = 0.f, h1 = 0.f, v0 = 0.f, v1 = 0.f;
            float xq0 = rp[0 * SSTRIDE];
            float xq1 = rp[1 * SSTRIDE];
            float xq2 = rp[2 * SSTRIDE];
            #pragma unroll
            for (int ts = 0; ts < 30; ts += 3) {
                SSTEP_PRE(ts + 0, xq0); xq0 = rp[SSTRIDE * (ts + 3)];
                SSTEP_PRE(ts + 1, xq1); xq1 = rp[SSTRIDE * (ts + 4)];
                SSTEP_PRE(ts + 2, xq2); xq2 = rp[SSTRIDE * (ts + 5)];
            }
            SSTEP_PRE(30, xq0); xq0 = rp[SSTRIDE * 33];
            #pragma unroll
            for (int ts = 31; ts < 61; ts += 3) {
                SSTEP_POST(ts + 0, xq1); xq1 = rp[SSTRIDE * (ts + 3)];
                SSTEP_POST(ts + 1, xq2); xq2 = rp[SSTRIDE * (ts + 4)];
                SSTEP_POST(ts + 2, xq0); xq0 = rp[SSTRIDE * (ts + 5)];
            }
            SSTEP_POST(61, xq1);
            SSTEP_POST(62, xq2);
        } else {
            // -------- memory waves (R7 order: issue, drain, stage) --------
            float* bufO = xs + ((k + 1) & 1) * BUFF;
            if (k < TPB - 1) ISSUE(4 * bq + k + 1);      // head start
            if (k >= 1) DRAINTO(4 * bq + k - 1, bufO);   // read bufO first
            if (k < TPB - 1) STAGEFROM(bufO);            // consume same-phase L
        }
        soft_barrier();
    }

    // ---- epilogue: all 1024 threads drain tile 3 (nontemporal) ----
    {
        const int srow4 = t >> 2;
        const int qq4   = (t & 3) * 4;
        const float* bufE = xs + ((TPB - 1) & 1) * BUFF;
        float* op = out + (size_t)srow4 * (BSZ * DIM)
                        + (size_t)(4 * bq + TPB - 1) * DIM + d0 + qq4;
        #pragma unroll
        for (int k2 = 0; k2 < 4; ++k2) {
            const float* p = bufE + SSTRIDE * (srow4 + 256 * k2) + qq4;
            vfloat4 v; v.x = p[0]; v.y = p[1]; v.z = p[2]; v.w = p[3];
            __builtin_nontemporal_store(v, reinterpret_cast<vfloat4*>(
                op + (size_t)k2 * (256 * BSZ * DIM)));
        }
    }
}

extern "C" void kernel_launch(void* const* d_in, const int* in_sizes, int n_in,
                              void* d_out, int out_size, void* d_ws, size_t ws_size,
                              hipStream_t stream) {
    const float* x     = (const float*)d_in[0];
    const float* A1    = (const float*)d_in[1];
    const float* A2    = (const float*)d_in[2];
    const float* B1    = (const float*)d_in[3];
    const float* B2    = (const float*)d_in[4];
    const float* C1    = (const float*)d_in[5];
    const float* C2    = (const float*)d_in[6];
    const float* omega = (const float*)d_in[7];
    float* out = (float*)d_out;

    (void)hipFuncSetAttribute(reinterpret_cast<const void*>(ssm2d_kernel),
                              hipFuncAttributeMaxDynamicSharedMemorySize, LDSB);

    dim3 grid(256);                 // 64 d-groups x 4 b-quads; 4 tiles/block
    dim3 block(THREADS);
    hipLaunchKernelGGL(ssm2d_kernel, grid, block, LDSB, stream,
                       x, A1, A2, B1, B2, C1, C2, omega, out);
}